// Round 4
// baseline (186.805 us; speedup 1.0000x reference)
//
#include <hip/hip_runtime.h>

// SmoothL1 (beta=0.5) masked sum reduction, N = 16M fixed.
// sl1 = ad < 0.5 ? d*d : ad - 0.25  (0.5*d*d/0.5 == d*d exactly: pow-2)
// mask: ad >= 1.0f/len; out[0] = sum(mask ? sl1 : 0)
//
// Ladder: plain=73us (L2-allocate wall ~2.75 TB/s) | nt=51us | nt+depth2=45.6us
// (bypass wall ~4.4 TB/s, MLP saturated). FETCH_SIZE stuck at exactly half
// across ALL policies -> artifact (half the TCC channels counted); model:
// full 192 MiB streams from memory every launch.
//
// R9: PATH PARTITION. Two independent walls observed: L2-allocate path
// ~2.75 TB/s, bypass path ~4.4 TB/s. All-nt leaves the L2 path idle. Route
// lens (1/3 of bytes, 67MB) through plain cached loads, keep outs+labels
// (134MB) on nt. At the 6.3 TB/s HBM ceiling (32us): nt demand 4.2 < 4.4,
// L2-path demand 2.1 < 2.75 -> balanced split lands on the roofline.
// Predict: 45.6 -> 33-38us. Neutral => wall is HBM-side; regress => L2
// machinery is global, revert.
// FP summation order bit-identical to R8 (absmax 0.0 - keep it).

#define N_TOTAL 16777216
#define NVEC    (N_TOTAL / 4)       // 4194304 vec4 groups
#define BLOCK   256
#define GRID    2048                // 8 blocks/CU, 32 waves/CU
#define ITERS   (NVEC / (BLOCK * GRID))   // 8 iterations/thread, exact cover

typedef float f32x4 __attribute__((ext_vector_type(4)));
typedef int   i32x4 __attribute__((ext_vector_type(4)));

__device__ __forceinline__ float sl1_term(float o, float l, int len) {
    float d  = o - l;
    float ad = fabsf(d);
    float v  = (ad < 0.5f) ? (d * d) : (ad - 0.25f);
    float boundary = 1.0f / (float)len;   // IEEE divide; matches jnp 1/len
    return (ad >= boundary) ? v : 0.0f;
}

__device__ __forceinline__ float consume4(f32x4 o, f32x4 l, i32x4 n) {
    float s = 0.0f;
    s += sl1_term(o.x, l.x, n.x);
    s += sl1_term(o.y, l.y, n.y);
    s += sl1_term(o.z, l.z, n.z);
    s += sl1_term(o.w, l.w, n.w);
    return s;
}

__global__ __launch_bounds__(BLOCK, 8) void RegressionLoss_45440753992375_kernel(
        const float* __restrict__ outs,
        const float* __restrict__ labels,
        const int*   __restrict__ lens,
        float* __restrict__ out) {
    const f32x4* o4 = (const f32x4*)outs;
    const f32x4* l4 = (const f32x4*)labels;
    const i32x4* n4 = (const i32x4*)lens;

    // Block-contiguous: block b owns [b*BLOCK*ITERS, ...), thread strides BLOCK.
    const int base = blockIdx.x * (BLOCK * ITERS) + threadIdx.x;

    // Pipeline prologue: iterations 0 and 1 in flight (6 loads).
    // outs/labels: nt (L2 bypass). lens: PLAIN (rides the L2-allocate path).
    f32x4 oA = __builtin_nontemporal_load(o4 + base);
    f32x4 lA = __builtin_nontemporal_load(l4 + base);
    i32x4 nA = n4[base];

    f32x4 oB = __builtin_nontemporal_load(o4 + base + BLOCK);
    f32x4 lB = __builtin_nontemporal_load(l4 + base + BLOCK);
    i32x4 nB = n4[base + BLOCK];

    float acc = 0.0f;
    #pragma unroll
    for (int it = 0; it < ITERS - 2; ++it) {
        // Issue iteration it+2 (9 outstanding) before consuming iteration it.
        const int idx = base + (it + 2) * BLOCK;
        f32x4 oC = __builtin_nontemporal_load(o4 + idx);
        f32x4 lC = __builtin_nontemporal_load(l4 + idx);
        i32x4 nC = n4[idx];

        acc += consume4(oA, lA, nA);

        // Rotate stages (register renaming; loop fully unrolled).
        oA = oB; lA = lB; nA = nB;
        oB = oC; lB = lC; nB = nC;
    }
    acc += consume4(oA, lA, nA);   // iteration ITERS-2
    acc += consume4(oB, lB, nB);   // iteration ITERS-1

    // wave-64 shuffle reduction
    #pragma unroll
    for (int off = 32; off > 0; off >>= 1)
        acc += __shfl_down(acc, off, 64);

    __shared__ float smem[BLOCK / 64];
    const int lane = threadIdx.x & 63;
    const int wid  = threadIdx.x >> 6;
    if (lane == 0) smem[wid] = acc;
    __syncthreads();
    if (threadIdx.x == 0) {
        float bsum = smem[0] + smem[1] + smem[2] + smem[3];
        atomicAdd(out, bsum);   // device-scope by default on CDNA
    }
}

extern "C" void kernel_launch(void* const* d_in, const int* in_sizes, int n_in,
                              void* d_out, int out_size, void* d_ws, size_t ws_size,
                              hipStream_t stream) {
    const float* outs   = (const float*)d_in[0];
    const float* labels = (const float*)d_in[1];
    const int*   lens   = (const int*)d_in[2];
    float* out = (float*)d_out;

    // d_out is poisoned 0xAA before every timed launch — zero it on-stream.
    hipMemsetAsync(out, 0, sizeof(float), stream);

    RegressionLoss_45440753992375_kernel<<<GRID, BLOCK, 0, stream>>>(outs, labels, lens, out);
}

// Round 5
// 182.805 us; speedup vs baseline: 1.0219x; 1.0219x over previous
//
#include <hip/hip_runtime.h>

// SmoothL1 (beta=0.5) masked sum reduction, N = 16M fixed.
// sl1 = ad < 0.5 ? d*d : ad - 0.25  (0.5*d*d/0.5 == d*d exactly: pow-2)
// mask: ad >= 1.0f/len; out[0] = sum(mask ? sl1 : 0)
//
// Ladder: plain=73us | sc1/sc0sc1=74-75us | nt depth1=51us | nt depth2=45.6us
// (4.4 TB/s). R9 path-partition (lens via L2) REGRESSED to 52us -> the
// L2-allocate machinery throttles globally; single delivery path, nt keeps it
// clean. FETCH_SIZE stuck at exactly half across all policies -> counter
// artifact, full 192 MiB streams every launch.
//
// R10: concurrency probe. Revert to R8 (all-nt) and deepen pipeline to
// depth-3: 12 dwordx4 (12 KB) in flight per thread. Everything else
// bit-identical (per-thread element order preserved -- absmax has been
// exactly 0.0 with this order; do not perturb).
// Predict: concurrency-limited -> 42-44us; memory-side wall -> neutral 45-47us
// and the roofline argument is complete.

#define N_TOTAL 16777216
#define NVEC    (N_TOTAL / 4)       // 4194304 vec4 groups
#define BLOCK   256
#define GRID    2048                // 8 blocks/CU, 32 waves/CU
#define ITERS   (NVEC / (BLOCK * GRID))   // 8 iterations/thread, exact cover

typedef float f32x4 __attribute__((ext_vector_type(4)));
typedef int   i32x4 __attribute__((ext_vector_type(4)));

__device__ __forceinline__ float sl1_term(float o, float l, int len) {
    float d  = o - l;
    float ad = fabsf(d);
    float v  = (ad < 0.5f) ? (d * d) : (ad - 0.25f);
    float boundary = 1.0f / (float)len;   // IEEE divide; matches jnp 1/len
    return (ad >= boundary) ? v : 0.0f;
}

__device__ __forceinline__ float consume4(f32x4 o, f32x4 l, i32x4 n) {
    float s = 0.0f;
    s += sl1_term(o.x, l.x, n.x);
    s += sl1_term(o.y, l.y, n.y);
    s += sl1_term(o.z, l.z, n.z);
    s += sl1_term(o.w, l.w, n.w);
    return s;
}

__global__ __launch_bounds__(BLOCK, 8) void RegressionLoss_45440753992375_kernel(
        const float* __restrict__ outs,
        const float* __restrict__ labels,
        const int*   __restrict__ lens,
        float* __restrict__ out) {
    const f32x4* o4 = (const f32x4*)outs;
    const f32x4* l4 = (const f32x4*)labels;
    const i32x4* n4 = (const i32x4*)lens;

    // Block-contiguous: block b owns [b*BLOCK*ITERS, ...), thread strides BLOCK.
    const int base = blockIdx.x * (BLOCK * ITERS) + threadIdx.x;

    // Pipeline prologue: iterations 0,1,2 in flight (9 loads).
    f32x4 oA = __builtin_nontemporal_load(o4 + base);
    f32x4 lA = __builtin_nontemporal_load(l4 + base);
    i32x4 nA = __builtin_nontemporal_load(n4 + base);

    f32x4 oB = __builtin_nontemporal_load(o4 + base + BLOCK);
    f32x4 lB = __builtin_nontemporal_load(l4 + base + BLOCK);
    i32x4 nB = __builtin_nontemporal_load(n4 + base + BLOCK);

    f32x4 oC = __builtin_nontemporal_load(o4 + base + 2 * BLOCK);
    f32x4 lC = __builtin_nontemporal_load(l4 + base + 2 * BLOCK);
    i32x4 nC = __builtin_nontemporal_load(n4 + base + 2 * BLOCK);

    float acc = 0.0f;
    #pragma unroll
    for (int it = 0; it < ITERS - 3; ++it) {
        // Issue iteration it+3 (12 outstanding) before consuming iteration it.
        const int idx = base + (it + 3) * BLOCK;
        f32x4 oD = __builtin_nontemporal_load(o4 + idx);
        f32x4 lD = __builtin_nontemporal_load(l4 + idx);
        i32x4 nD = __builtin_nontemporal_load(n4 + idx);

        acc += consume4(oA, lA, nA);

        // Rotate stages (register renaming; loop fully unrolled).
        oA = oB; lA = lB; nA = nB;
        oB = oC; lB = lC; nB = nC;
        oC = oD; lC = lD; nC = nD;
    }
    acc += consume4(oA, lA, nA);   // iteration ITERS-3
    acc += consume4(oB, lB, nB);   // iteration ITERS-2
    acc += consume4(oC, lC, nC);   // iteration ITERS-1

    // wave-64 shuffle reduction
    #pragma unroll
    for (int off = 32; off > 0; off >>= 1)
        acc += __shfl_down(acc, off, 64);

    __shared__ float smem[BLOCK / 64];
    const int lane = threadIdx.x & 63;
    const int wid  = threadIdx.x >> 6;
    if (lane == 0) smem[wid] = acc;
    __syncthreads();
    if (threadIdx.x == 0) {
        float bsum = smem[0] + smem[1] + smem[2] + smem[3];
        atomicAdd(out, bsum);   // device-scope by default on CDNA
    }
}

extern "C" void kernel_launch(void* const* d_in, const int* in_sizes, int n_in,
                              void* d_out, int out_size, void* d_ws, size_t ws_size,
                              hipStream_t stream) {
    const float* outs   = (const float*)d_in[0];
    const float* labels = (const float*)d_in[1];
    const int*   lens   = (const int*)d_in[2];
    float* out = (float*)d_out;

    // d_out is poisoned 0xAA before every timed launch — zero it on-stream.
    hipMemsetAsync(out, 0, sizeof(float), stream);

    RegressionLoss_45440753992375_kernel<<<GRID, BLOCK, 0, stream>>>(outs, labels, lens, out);
}